// Round 1
// baseline (573.843 us; speedup 1.0000x reference)
//
#include <hip/hip_runtime.h>

typedef unsigned short u16;
typedef __attribute__((ext_vector_type(8))) short bf16x8;
typedef __attribute__((ext_vector_type(4))) float f32x4;

__device__ __forceinline__ u16 f2bf(float f) {
  unsigned u = __float_as_uint(f);
  u += 0x7FFFu + ((u >> 16) & 1u);
  return (u16)(u >> 16);
}
__device__ __forceinline__ float bf2f(u16 h) {
  return __uint_as_float(((unsigned)h) << 16);
}

#define GLOAD16(g, l) __builtin_amdgcn_global_load_lds( \
    (const __attribute__((address_space(1))) void*)(g), \
    (__attribute__((address_space(3))) void*)(l), 16, 0, 0)

// ---------- elementwise converts ----------
__global__ __launch_bounds__(256) void cvtw_kernel(const float* __restrict__ in,
                                                   u16* __restrict__ out, int n4) {
  int i = blockIdx.x * 256 + threadIdx.x;
  if (i >= n4) return;
  float4 f = ((const float4*)in)[i];
  ushort4 u;
  u.x = f2bf(f.x); u.y = f2bf(f.y); u.z = f2bf(f.z); u.w = f2bf(f.w);
  ((ushort4*)out)[i] = u;
}

// gather x chunk: rows = ((s-s0)*128 + b)*4 + m , from hidden[s][m][b][0][h]
__global__ __launch_bounds__(256) void xcvt_kernel(const float* __restrict__ hidden,
                                                   u16* __restrict__ xb, int s0) {
  int idx = blockIdx.x * 256 + threadIdx.x;      // 0 .. 8192*256-1
  int h4 = idx & 255;
  int lrow = idx >> 8;                           // 0..8191
  int m = lrow & 3;
  int b = (lrow >> 2) & 127;
  int sl = lrow >> 9;                            // 0..15
  int s = s0 + sl;
  const float4 f = *(const float4*)(hidden + (((size_t)(s * 4 + m) * 128 + b) * 1024) + h4 * 4);
  ushort4 u;
  u.x = f2bf(f.x); u.y = f2bf(f.y); u.z = f2bf(f.z); u.w = f2bf(f.w);
  *(ushort4*)(xb + (size_t)lrow * 1024 + h4 * 4) = u;
}

// ---------- GEMM: C[m,n] = sum_k A[m,k]*B[n,k] + bias[n], bf16 in, MFMA 16x16x32 ----------
// MODE 0: bf16 out, C[row*N+col]
// MODE 1: bf16 out, row t -> s=t>>7,b=t&127, u=b*64+s; += pos_enc[s][col]
// MODE 2: f32 out, row u -> s=u&63,b=u>>6; out[(s*128+b)*1024+col]
template <int MODE>
__global__ __launch_bounds__(256) void gemm_bt(const u16* __restrict__ A,
                                               const u16* __restrict__ Bw,
                                               const float* __restrict__ bias,
                                               void* __restrict__ Cout,
                                               int M, int N, int K,
                                               const float* __restrict__ posenc) {
  __shared__ u16 As[128 * 32];
  __shared__ u16 Bs[128 * 32];
  const int t = threadIdx.x;
  const int w = t >> 6, l = t & 63;
  const int rowBase = blockIdx.y * 128, colBase = blockIdx.x * 128;
  const int wr = (w >> 1) * 64, wc = (w & 1) * 64;
  const int lr = l & 15, lg = l >> 4;
  const int sl = (lg ^ (lr & 3)) * 8;   // swizzled frag slot (elements)

  // staging: flat = c*256 + t ; row = flat>>2 ; phys slot = flat&3 ; fetch global slot = phys ^ (row&3)
  const int r0 = t >> 2,         s0 = (((t) & 3) ^ (r0 & 3)) * 8;
  const int r1 = (t + 256) >> 2, s1 = (((t + 256) & 3) ^ (r1 & 3)) * 8;
  const u16* A0 = A + (size_t)(rowBase + r0) * K + s0;
  const u16* A1 = A + (size_t)(rowBase + r1) * K + s1;
  const u16* B0 = Bw + (size_t)(colBase + r0) * K + s0;
  const u16* B1 = Bw + (size_t)(colBase + r1) * K + s1;
  u16* lA0 = As + (w * 64) * 8;
  u16* lA1 = As + (256 + w * 64) * 8;
  u16* lB0 = Bs + (w * 64) * 8;
  u16* lB1 = Bs + (256 + w * 64) * 8;

  f32x4 acc[4][4];
#pragma unroll
  for (int i = 0; i < 4; i++)
#pragma unroll
    for (int j = 0; j < 4; j++) acc[i][j] = (f32x4){0.f, 0.f, 0.f, 0.f};

  for (int k0 = 0; k0 < K; k0 += 32) {
    GLOAD16(A0 + k0, lA0);
    GLOAD16(A1 + k0, lA1);
    GLOAD16(B0 + k0, lB0);
    GLOAD16(B1 + k0, lB1);
    __syncthreads();
    bf16x8 af[4], bfv[4];
#pragma unroll
    for (int i = 0; i < 4; i++) af[i] = *(const bf16x8*)(As + (wr + i * 16 + lr) * 32 + sl);
#pragma unroll
    for (int j = 0; j < 4; j++) bfv[j] = *(const bf16x8*)(Bs + (wc + j * 16 + lr) * 32 + sl);
#pragma unroll
    for (int i = 0; i < 4; i++)
#pragma unroll
      for (int j = 0; j < 4; j++)
        acc[i][j] = __builtin_amdgcn_mfma_f32_16x16x32_bf16(af[i], bfv[j], acc[i][j], 0, 0, 0);
    __syncthreads();
  }

  const int orow0 = rowBase + wr + lg * 4;
  const int ocol0 = colBase + wc + lr;
#pragma unroll
  for (int i = 0; i < 4; i++) {
#pragma unroll
    for (int j = 0; j < 4; j++) {
#pragma unroll
      for (int r = 0; r < 4; r++) {
        int row = orow0 + i * 16 + r;
        int col = ocol0 + j * 16;
        float v = acc[i][j][r] + bias[col];
        if (MODE == 0) {
          ((u16*)Cout)[(size_t)row * N + col] = f2bf(v);
        } else if (MODE == 1) {
          int s = row >> 7, b = row & 127;
          v += posenc[s * 1024 + col];
          ((u16*)Cout)[((size_t)(b * 64 + s)) * 1024 + col] = f2bf(v);
        } else {
          int s = row & 63, b = row >> 6;
          ((float*)Cout)[((size_t)(s * 128 + b)) * 1024 + col] = v;
        }
      }
    }
  }
}

// ---------- attention A: L=4, per (seq,head) one wave; outputs mean over the 4 queries ----------
__global__ __launch_bounds__(256) void attn1_kernel(const u16* __restrict__ qkv,
                                                    u16* __restrict__ am, int seqBase) {
  const int w = threadIdx.x >> 6, l = threadIdx.x & 63;
  const int pair = blockIdx.x * 4 + w;   // 0..16383
  const int seq = pair >> 3, head = pair & 7;
  const int d0 = l * 2;
  const u16* base = qkv + (size_t)(seq * 4) * 3072 + head * 128 + d0;
  const float scale = 0.08838834764831845f;  // 1/sqrt(128)
  float q[4][2], k[4][2], v[4][2];
#pragma unroll
  for (int m = 0; m < 4; m++) {
    ushort2 uq = *(const ushort2*)(base + (size_t)m * 3072);
    ushort2 uk = *(const ushort2*)(base + (size_t)m * 3072 + 1024);
    ushort2 uv = *(const ushort2*)(base + (size_t)m * 3072 + 2048);
    q[m][0] = bf2f(uq.x) * scale; q[m][1] = bf2f(uq.y) * scale;
    k[m][0] = bf2f(uk.x);         k[m][1] = bf2f(uk.y);
    v[m][0] = bf2f(uv.x);         v[m][1] = bf2f(uv.y);
  }
  float sc[4][4];
#pragma unroll
  for (int i = 0; i < 4; i++)
#pragma unroll
    for (int j = 0; j < 4; j++)
      sc[i][j] = q[i][0] * k[j][0] + q[i][1] * k[j][1];
#pragma unroll
  for (int off = 32; off >= 1; off >>= 1)
#pragma unroll
    for (int i = 0; i < 4; i++)
#pragma unroll
      for (int j = 0; j < 4; j++)
        sc[i][j] += __shfl_xor(sc[i][j], off, 64);
  float pbar[4] = {0.f, 0.f, 0.f, 0.f};
#pragma unroll
  for (int i = 0; i < 4; i++) {
    float mx = fmaxf(fmaxf(sc[i][0], sc[i][1]), fmaxf(sc[i][2], sc[i][3]));
    float e0 = __expf(sc[i][0] - mx), e1 = __expf(sc[i][1] - mx);
    float e2 = __expf(sc[i][2] - mx), e3 = __expf(sc[i][3] - mx);
    float inv = 0.25f / (e0 + e1 + e2 + e3);
    pbar[0] += e0 * inv; pbar[1] += e1 * inv; pbar[2] += e2 * inv; pbar[3] += e3 * inv;
  }
  float o0 = pbar[0] * v[0][0] + pbar[1] * v[1][0] + pbar[2] * v[2][0] + pbar[3] * v[3][0];
  float o1 = pbar[0] * v[0][1] + pbar[1] * v[1][1] + pbar[2] * v[2][1] + pbar[3] * v[3][1];
  ushort2 ou; ou.x = f2bf(o0); ou.y = f2bf(o1);
  *(ushort2*)(am + (size_t)(seqBase + seq) * 1024 + head * 128 + d0) = ou;
}

// ---------- attention B: L=64, one block per (b,head); full-tile MFMA attention ----------
__global__ __launch_bounds__(256) void attn2_kernel(const u16* __restrict__ qkv2,
                                                    u16* __restrict__ aout) {
  __shared__ u16 Qs[64 * 128];   // slot-swizzled (16B slots, slot ^= row&7)
  __shared__ u16 Ks[64 * 128];
  __shared__ u16 Vt[128 * 72];   // transposed V, padded rows (72 elems = 144B)
  __shared__ u16 Ps[64 * 72];    // probabilities, padded
  const int t = threadIdx.x, w = t >> 6, l = t & 63;
  const int lr = l & 15, lg = l >> 4;
  const int b = blockIdx.x >> 3, head = blockIdx.x & 7;
  const u16* qb = qkv2 + (size_t)(b * 64) * 3072 + head * 128;

  // stage Q,K via global_load_lds with pre-swizzled source
#pragma unroll
  for (int c = 0; c < 4; c++) {
    int flat = c * 256 + t;
    int row = flat >> 4, sp = flat & 15;
    int sg = (sp ^ (row & 7)) * 8;
    GLOAD16(qb + (size_t)row * 3072 + sg, Qs + (c * 256 + w * 64) * 8);
    GLOAD16(qb + 1024 + (size_t)row * 3072 + sg, Ks + (c * 256 + w * 64) * 8);
  }
  // stage V transposed (reg-staged)
  const int dd = (t & 63) * 2, kb = t >> 6;
#pragma unroll
  for (int c = 0; c < 16; c++) {
    int k = c * 4 + kb;
    ushort2 vv = *(const ushort2*)(qb + 2048 + (size_t)k * 3072 + dd);
    Vt[(size_t)dd * 72 + k] = vv.x;
    Vt[(size_t)(dd + 1) * 72 + k] = vv.y;
  }
  __syncthreads();

  // QK^T: wave w owns score rows [w*16, w*16+16)
  f32x4 sc[4];
#pragma unroll
  for (int cb = 0; cb < 4; cb++) sc[cb] = (f32x4){0.f, 0.f, 0.f, 0.f};
#pragma unroll
  for (int ks = 0; ks < 4; ks++) {
    bf16x8 aq = *(const bf16x8*)(Qs + (w * 16 + lr) * 128 + ((ks * 4 + lg) ^ (lr & 7)) * 8);
#pragma unroll
    for (int cb = 0; cb < 4; cb++) {
      bf16x8 bk = *(const bf16x8*)(Ks + (cb * 16 + lr) * 128 + ((ks * 4 + lg) ^ (lr & 7)) * 8);
      sc[cb] = __builtin_amdgcn_mfma_f32_16x16x32_bf16(aq, bk, sc[cb], 0, 0, 0);
    }
  }

  // softmax rows (fp32), write P to LDS as bf16
  const float scale = 0.08838834764831845f;
#pragma unroll
  for (int r = 0; r < 4; r++) {
#pragma unroll
    for (int cb = 0; cb < 4; cb++) sc[cb][r] *= scale;
    float mx = fmaxf(fmaxf(sc[0][r], sc[1][r]), fmaxf(sc[2][r], sc[3][r]));
#pragma unroll
    for (int off = 1; off < 16; off <<= 1) mx = fmaxf(mx, __shfl_xor(mx, off, 64));
    float sum = 0.f;
#pragma unroll
    for (int cb = 0; cb < 4; cb++) {
      float e = __expf(sc[cb][r] - mx);
      sum += e;
      sc[cb][r] = e;
    }
#pragma unroll
    for (int off = 1; off < 16; off <<= 1) sum += __shfl_xor(sum, off, 64);
    float inv = 1.f / sum;
    int prow = w * 16 + lg * 4 + r;
#pragma unroll
    for (int cb = 0; cb < 4; cb++)
      Ps[(size_t)prow * 72 + cb * 16 + lr] = f2bf(sc[cb][r] * inv);
  }

  // PV: out rows = same stripe, cols d = 0..127
  f32x4 o[8];
#pragma unroll
  for (int cb = 0; cb < 8; cb++) o[cb] = (f32x4){0.f, 0.f, 0.f, 0.f};
#pragma unroll
  for (int ks = 0; ks < 2; ks++) {
    bf16x8 ap = *(const bf16x8*)(Ps + (w * 16 + lr) * 72 + ks * 32 + lg * 8);
#pragma unroll
    for (int cb = 0; cb < 8; cb++) {
      bf16x8 bv = *(const bf16x8*)(Vt + (cb * 16 + lr) * 72 + ks * 32 + lg * 8);
      o[cb] = __builtin_amdgcn_mfma_f32_16x16x32_bf16(ap, bv, o[cb], 0, 0, 0);
    }
  }
#pragma unroll
  for (int cb = 0; cb < 8; cb++) {
#pragma unroll
    for (int r = 0; r < 4; r++) {
      int srow = w * 16 + lg * 4 + r;
      int d = cb * 16 + lr;
      aout[(size_t)(b * 64 + srow) * 1024 + head * 128 + d] = f2bf(o[cb][r]);
    }
  }
}

extern "C" void kernel_launch(void* const* d_in, const int* in_sizes, int n_in,
                              void* d_out, int out_size, void* d_ws, size_t ws_size,
                              hipStream_t stream) {
  const float* hidden   = (const float*)d_in[0];
  const float* mf_in_w  = (const float*)d_in[1];
  const float* mf_in_b  = (const float*)d_in[2];
  const float* mf_out_w = (const float*)d_in[3];
  const float* mf_out_b = (const float*)d_in[4];
  const float* sf_in_w  = (const float*)d_in[5];
  const float* sf_in_b  = (const float*)d_in[6];
  const float* sf_out_w = (const float*)d_in[7];
  const float* sf_out_b = (const float*)d_in[8];
  const float* pos_enc  = (const float*)d_in[9];

  char* ws = (char*)d_ws;
  u16* w_mf_in  = (u16*)(ws);              // 3072*1024*2 = 6291456
  u16* w_mf_out = (u16*)(ws + 6291456);    // 1024*1024*2 = 2097152
  u16* w_sf_in  = (u16*)(ws + 8388608);    // 6291456
  u16* w_sf_out = (u16*)(ws + 14680064);   // 2097152
  u16* xchunk   = (u16*)(ws + 16777216);   // 8192*1024*2 = 16777216
  u16* qkvbuf   = (u16*)(ws + 33554432);   // 8192*3072*2 = 50331648
  u16* attnmean = (u16*)(ws + 83886080);   // 16777216
  u16* seqbuf   = (u16*)(ws + 100663296);  // 16777216
  u16* a2out    = (u16*)(ws + 117440512);  // 16777216 -> total 134217728 (128 MB)

  cvtw_kernel<<<3072, 256, 0, stream>>>(mf_in_w, w_mf_in, 786432);
  cvtw_kernel<<<1024, 256, 0, stream>>>(mf_out_w, w_mf_out, 262144);
  cvtw_kernel<<<3072, 256, 0, stream>>>(sf_in_w, w_sf_in, 786432);
  cvtw_kernel<<<1024, 256, 0, stream>>>(sf_out_w, w_sf_out, 262144);

  for (int c = 0; c < 4; ++c) {
    xcvt_kernel<<<8192, 256, 0, stream>>>(hidden, xchunk, c * 16);
    gemm_bt<0><<<dim3(24, 64), 256, 0, stream>>>(xchunk, w_mf_in, mf_in_b, qkvbuf,
                                                 8192, 3072, 1024, nullptr);
    attn1_kernel<<<4096, 256, 0, stream>>>(qkvbuf, attnmean, c * 2048);
  }

  gemm_bt<1><<<dim3(8, 64), 256, 0, stream>>>(attnmean, w_mf_out, mf_out_b, seqbuf,
                                              8192, 1024, 1024, pos_enc);
  gemm_bt<0><<<dim3(24, 64), 256, 0, stream>>>(seqbuf, w_sf_in, sf_in_b, qkvbuf,
                                               8192, 3072, 1024, nullptr);
  attn2_kernel<<<1024, 256, 0, stream>>>(qkvbuf, a2out);
  gemm_bt<2><<<dim3(8, 64), 256, 0, stream>>>(a2out, w_sf_out, sf_out_b, d_out,
                                              8192, 1024, 1024, nullptr);
}